// Round 8
// baseline (317.637 us; speedup 1.0000x reference)
//
#include <hip/hip_runtime.h>
#include <math.h>

#define B_ 128
#define L_ 200
#define C_ 300
#define K_ 128
#define A_ 5000
#define F_ 64
#define D_ 512
#define CP_ 320      // padded C
#define LP_ 260      // padded L rows
#define NPAD_ 5056   // 79*64
#define KP2_ 10048   // 157*64 (padded 2A)
#define KP1_ 5056    // 79*64  (padded A)

typedef __attribute__((ext_vector_type(8))) short bf16x8;
typedef __attribute__((ext_vector_type(8))) short short8;
typedef __attribute__((ext_vector_type(4))) float f32x4;

#define MFMA(a,b,c) __builtin_amdgcn_mfma_f32_16x16x32_bf16(a,b,c,0,0,0)

// swizzle-free padded LDS row offset (shorts): 64B rows + 16B pad every 4 rows
#define ROFF(r) ((r)*32 + ((r)>>2)*8)

static __device__ __forceinline__ unsigned short f2bf(float f) {
    unsigned u = __float_as_uint(f);
    unsigned r = (u + 0x7FFFu + ((u >> 16) & 1u)) >> 16;
    return (unsigned short)r;
}

// ---------------- workspace layout (float offsets) ----------------
#define OFF_XP     ((size_t)0)            // 5,324,800
#define OFF_WP     ((size_t)5324800)      // 286,720
#define OFF_E      ((size_t)5611520)      // 65,536
#define OFF_EBF    ((size_t)5677056)      // 16,384
#define OFF_UST    ((size_t)5693440)      // 8,192
#define OFF_VB     ((size_t)5701632)      // 64
#define OFF_S2     ((size_t)5701696)      // 128
#define OFF_UMBF   ((size_t)5701824)      // 643,072
#define OFF_UFBF   ((size_t)6344896)      // 643,072
#define OFF_UMMFBF ((size_t)6987968)      // 323,584
#define OFF_PART   ((size_t)7311552)      // 12*128*5056

// ---------------- prep: x -> bf16 padded [128][260][320] ----------------
__global__ __launch_bounds__(320) void prep_x_kernel(const float* __restrict__ x, short* __restrict__ xp)
{
    const int row = blockIdx.x;
    const int b   = blockIdx.y;
    const int c   = threadIdx.x;
    float v = 0.f;
    if (row < L_ && c < C_) v = x[((size_t)b * L_ + row) * C_ + c];
    xp[((size_t)b * LP_ + row) * CP_ + c] = (short)f2bf(v);
}

// ---------------- prep: conv weights -> bf16 [br][k][tap][320] ----------------
__global__ void prep_w_kernel(const float* __restrict__ w2, const float* __restrict__ w3,
                              const float* __restrict__ w4, const float* __restrict__ w5,
                              short* __restrict__ wp)
{
    const int idx = blockIdx.x * 256 + threadIdx.x;
    if (idx >= 128 * 14 * CP_) return;
    int off, wsz; const float* src;
    if (idx < 81920)       { off = idx;          wsz = 2; src = w2; }
    else if (idx < 204800) { off = idx - 81920;  wsz = 3; src = w3; }
    else if (idx < 368640) { off = idx - 204800; wsz = 4; src = w4; }
    else                   { off = idx - 368640; wsz = 5; src = w5; }
    const int k   = off / (wsz * CP_);
    const int r   = off % (wsz * CP_);
    const int tap = r / CP_;
    const int c   = r % CP_;
    float v = 0.f;
    if (c < C_) v = src[((size_t)k * C_ + c) * wsz + tap];
    wp[idx] = (short)f2bf(v);
}

// ---------------- conv v4 body: one block per (b,br), M=256, N=128 ----------------
// 256 threads = 4 waves (2m x 2n), wave tile 128x64, acc[8][4]
template<int WSZ>
__device__ __forceinline__ void conv_body(
    const short* __restrict__ xbase, const short* __restrict__ wpb,
    const float* __restrict__ bp, float* __restrict__ e, short* __restrict__ ebf,
    int b, int br, short* lA, short* lB, float (*smax)[128])
{
    const int Pout = 199 - br;
    const int tid  = threadIdx.x;
    const int wave = tid >> 6;
    const int lane = tid & 63;
    const int mw   = wave & 1;          // rows mw*128
    const int nw   = wave >> 1;         // cols nw*64

    f32x4 acc[8][4];
    #pragma unroll
    for (int mf = 0; mf < 8; ++mf)
        #pragma unroll
        for (int nf = 0; nf < 4; ++nf)
            acc[mf][nf] = (f32x4){0.f, 0.f, 0.f, 0.f};

    short8 aR[5];
    short8 bR[2 * WSZ];

    // A chunk ch (16B): row=ch>>2 (0..259), half=ch&3
    #define LDA4(ch, cc) (*(const short8*)(xbase + (size_t)((ch) >> 2) * CP_ + (cc) * 32 + ((ch) & 3) * 8))
    // B chunk ch: r=ch>>2 = tap*128+fil, half=ch&3
    #define LDB4(ch, cc) (*(const short8*)(wpb + (size_t)(((ch) >> 2) & 127) * (WSZ * CP_) + (((ch) >> 2) >> 7) * CP_ + (cc) * 32 + ((ch) & 3) * 8))

    // prologue: cc = 0
    #pragma unroll
    for (int k = 0; k < 5; ++k) {
        const int ch = tid + k * 256;
        if (k < 4 || ch < 1040) aR[k] = LDA4(ch, 0);
    }
    #pragma unroll
    for (int k = 0; k < 2 * WSZ; ++k) bR[k] = LDB4(tid + k * 256, 0);

    for (int cc = 0; cc < 10; ++cc) {
        __syncthreads();           // prior MFMA reads done; staged loads drained
        #pragma unroll
        for (int k = 0; k < 5; ++k) {
            const int ch = tid + k * 256;
            if (k < 4 || ch < 1040)
                *(short8*)(lA + ROFF(ch >> 2) + (ch & 3) * 8) = aR[k];
        }
        #pragma unroll
        for (int k = 0; k < 2 * WSZ; ++k) {
            const int ch = tid + k * 256;
            *(short8*)(lB + ROFF(ch >> 2) + (ch & 3) * 8) = bR[k];
        }
        __syncthreads();           // LDS visible
        if (cc + 1 < 10) {         // issue next slice: overlaps MFMA below
            #pragma unroll
            for (int k = 0; k < 5; ++k) {
                const int ch = tid + k * 256;
                if (k < 4 || ch < 1040) aR[k] = LDA4(ch, cc + 1);
            }
            #pragma unroll
            for (int k = 0; k < 2 * WSZ; ++k) bR[k] = LDB4(tid + k * 256, cc + 1);
        }
        #pragma unroll
        for (int tap = 0; tap < WSZ; ++tap) {
            bf16x8 bfr[4];
            #pragma unroll
            for (int nf = 0; nf < 4; ++nf)
                bfr[nf] = *(const bf16x8*)(lB + ROFF(tap * 128 + nw * 64 + nf * 16 + (lane & 15)) + (lane >> 4) * 8);
            #pragma unroll
            for (int mf = 0; mf < 8; ++mf) {
                const bf16x8 af = *(const bf16x8*)(lA + ROFF(mw * 128 + mf * 16 + (lane & 15) + tap) + (lane >> 4) * 8);
                #pragma unroll
                for (int nf = 0; nf < 4; ++nf)
                    acc[mf][nf] = MFMA(af, bfr[nf], acc[mf][nf]);
            }
        }
    }
    #undef LDA4
    #undef LDB4

    // epilogue: masked max over positions
    float vm[4] = {-1e30f, -1e30f, -1e30f, -1e30f};
    #pragma unroll
    for (int mf = 0; mf < 8; ++mf) {
        const int rowbase = mw * 128 + mf * 16 + (lane >> 4) * 4;
        #pragma unroll
        for (int r = 0; r < 4; ++r) {
            const bool valid = (rowbase + r) < Pout;
            #pragma unroll
            for (int nf = 0; nf < 4; ++nf)
                vm[nf] = fmaxf(vm[nf], valid ? acc[mf][nf][r] : -1e30f);
        }
    }
    #pragma unroll
    for (int nf = 0; nf < 4; ++nf) {
        vm[nf] = fmaxf(vm[nf], __shfl_xor(vm[nf], 16));
        vm[nf] = fmaxf(vm[nf], __shfl_xor(vm[nf], 32));
    }
    if (lane < 16) {
        #pragma unroll
        for (int nf = 0; nf < 4; ++nf)
            smax[mw][nw * 64 + nf * 16 + lane] = vm[nf];
    }
    __syncthreads();
    if (tid < 128) {
        const float m = fmaxf(smax[0][tid], smax[1][tid]);
        const float val = fmaxf(bp[tid] + m, 0.f);
        e[(size_t)b * D_ + tid * 4 + br] = val;
        ebf[(size_t)b * D_ + tid * 4 + br] = (short)f2bf(val);
    }
}

// grid (b=128, br=4), block 256
__global__ __launch_bounds__(256) void conv_gemm4_kernel(
    const short* __restrict__ xp, const short* __restrict__ wp,
    const float* __restrict__ b2, const float* __restrict__ b3,
    const float* __restrict__ b4, const float* __restrict__ b5,
    float* __restrict__ e, short* __restrict__ ebf)
{
    __shared__ short lA[8832];      // ROFF(259)+32
    __shared__ short lB[21752];     // ROFF(639)+32
    __shared__ float smax[2][128];

    const int b  = blockIdx.x;
    const int br = blockIdx.y;
    const short* xbase = xp + (size_t)b * LP_ * CP_;

    if (br == 0)      conv_body<2>(xbase, wp,          b2, e, ebf, b, 0, lA, lB, smax);
    else if (br == 1) conv_body<3>(xbase, wp + 81920,  b3, e, ebf, b, 1, lA, lB, smax);
    else if (br == 2) conv_body<4>(xbase, wp + 204800, b4, e, ebf, b, 2, lA, lB, smax);
    else              conv_body<5>(xbase, wp + 368640, b5, e, ebf, b, 3, lA, lB, smax);
}

// ---------------- big MFMA GEMM: K-phase 64, reg prefetch after barrier ----------
// grid (79, z), block 512 (8 waves: 4m x 2n), tile M=128 N=64
__global__ __launch_bounds__(512) void gemm3_kernel(
    const short* __restrict__ Abf, int Kpad,
    const float* __restrict__ W, int K, int N,
    int steps_per_z, float* __restrict__ partial)
{
    const int n0 = blockIdx.x * 64;
    const int total = Kpad >> 6;
    const int sbeg = blockIdx.y * steps_per_z;
    const int send = min(sbeg + steps_per_z, total);

    const int tid  = threadIdx.x;
    const int wave = tid >> 6;
    const int lane = tid & 63;
    const int mw   = wave & 3;
    const int nw   = wave >> 2;

    __shared__ short lA[128 * 68];
    __shared__ short lB[64 * 68];

    const int arow = tid >> 2, ac0 = (tid & 3) * 16;
    const int fil  = tid >> 3, wc0 = (tid & 7) * 8;

    f32x4 acc[2][2];
    #pragma unroll
    for (int mf = 0; mf < 2; ++mf)
        #pragma unroll
        for (int nf = 0; nf < 2; ++nf)
            acc[mf][nf] = (f32x4){0.f, 0.f, 0.f, 0.f};

    short8 ra0, ra1;
    float4 rw0, rw1;
    const bool wrow_ok = (n0 + fil) < N;

    {
        const int kb = sbeg * 64;
        ra0 = *(const short8*)(Abf + (size_t)arow * Kpad + kb + ac0);
        ra1 = *(const short8*)(Abf + (size_t)arow * Kpad + kb + ac0 + 8);
        rw0 = make_float4(0.f,0.f,0.f,0.f); rw1 = rw0;
        if (wrow_ok && (kb + wc0) < K)     rw0 = *(const float4*)(W + (size_t)(n0 + fil) * K + kb + wc0);
        if (wrow_ok && (kb + wc0 + 4) < K) rw1 = *(const float4*)(W + (size_t)(n0 + fil) * K + kb + wc0 + 4);
    }

    for (int s = sbeg; s < send; ++s) {
        __syncthreads();
        *(short8*)(lA + arow * 68 + ac0)     = ra0;
        *(short8*)(lA + arow * 68 + ac0 + 8) = ra1;
        {
            short8 wb;
            wb[0]=(short)f2bf(rw0.x); wb[1]=(short)f2bf(rw0.y); wb[2]=(short)f2bf(rw0.z); wb[3]=(short)f2bf(rw0.w);
            wb[4]=(short)f2bf(rw1.x); wb[5]=(short)f2bf(rw1.y); wb[6]=(short)f2bf(rw1.z); wb[7]=(short)f2bf(rw1.w);
            *(short8*)(lB + fil * 68 + wc0) = wb;
        }
        __syncthreads();
        if (s + 1 < send) {
            const int kb = (s + 1) * 64;
            ra0 = *(const short8*)(Abf + (size_t)arow * Kpad + kb + ac0);
            ra1 = *(const short8*)(Abf + (size_t)arow * Kpad + kb + ac0 + 8);
            float4 t0 = make_float4(0.f,0.f,0.f,0.f), t1 = t0;
            if (wrow_ok && (kb + wc0) < K)     t0 = *(const float4*)(W + (size_t)(n0 + fil) * K + kb + wc0);
            if (wrow_ok && (kb + wc0 + 4) < K) t1 = *(const float4*)(W + (size_t)(n0 + fil) * K + kb + wc0 + 4);
            rw0 = t0; rw1 = t1;
        }
        #pragma unroll
        for (int ks = 0; ks < 2; ++ks) {
            bf16x8 af[2], bfr[2];
            #pragma unroll
            for (int mf = 0; mf < 2; ++mf)
                af[mf] = *(const bf16x8*)(lA + (mw * 32 + mf * 16 + (lane & 15)) * 68 + ks * 32 + (lane >> 4) * 8);
            #pragma unroll
            for (int nf = 0; nf < 2; ++nf)
                bfr[nf] = *(const bf16x8*)(lB + (nw * 32 + nf * 16 + (lane & 15)) * 68 + ks * 32 + (lane >> 4) * 8);
            #pragma unroll
            for (int mf = 0; mf < 2; ++mf)
                #pragma unroll
                for (int nf = 0; nf < 2; ++nf)
                    acc[mf][nf] = MFMA(af[mf], bfr[nf], acc[mf][nf]);
        }
    }

    #pragma unroll
    for (int mf = 0; mf < 2; ++mf)
        #pragma unroll
        for (int nf = 0; nf < 2; ++nf)
            #pragma unroll
            for (int r = 0; r < 4; ++r) {
                const int row = mw * 32 + mf * 16 + (lane >> 4) * 4 + r;
                const int col = nw * 32 + nf * 16 + (lane & 15);
                partial[((size_t)blockIdx.y * B_ + row) * NPAD_ + n0 + col] = acc[mf][nf][r];
            }
}

// ---------------- reduce partials + bias (+tanh) -> bf16/fp32, fused pad ------
__global__ void reduce2_kernel(const float* __restrict__ partial, const float* __restrict__ bias,
                               float* __restrict__ outf, short* __restrict__ outb,
                               int N, int ldo, int ooff, int js, int act, int padn)
{
    const int Ntot = N + padn;
    const int idx = blockIdx.x * 256 + threadIdx.x;
    if (idx >= B_ * Ntot) return;
    const int n = idx % Ntot;
    const int b = idx / Ntot;
    if (n >= N) { outb[(size_t)b * ldo + ooff + n] = 0; return; }
    float s = bias[n];
    for (int k = 0; k < js; ++k) s += partial[((size_t)k * B_ + b) * NPAD_ + n];
    if (act) s = tanhf(s);
    if (outb) outb[(size_t)b * ldo + ooff + n] = (short)f2bf(s);
    else      outf[(size_t)b * ldo + ooff + n] = s;
}

// ---------------- ust: (128,64) = e @ fic_fc_w^T + b ----------------
__global__ __launch_bounds__(256) void ust_kernel(
    const float* __restrict__ e, const float* __restrict__ W,
    const float* __restrict__ bias, float* __restrict__ ust)
{
    const int b = blockIdx.x;
    const int f = threadIdx.x >> 2;
    const int q = threadIdx.x & 3;
    const float* er = e + (size_t)b * D_ + q * 128;
    const float* wr = W + (size_t)f * D_ + q * 128;
    float acc = 0.f;
    #pragma unroll
    for (int j = 0; j < 128; j += 4) {
        const float4 ev = *(const float4*)(er + j);
        const float4 wv = *(const float4*)(wr + j);
        acc += ev.x*wv.x + ev.y*wv.y + ev.z*wv.z + ev.w*wv.w;
    }
    acc += __shfl_xor(acc, 1);
    acc += __shfl_xor(acc, 2);
    if (q == 0) ust[(size_t)b * F_ + f] = acc + bias[f];
}

// ---------------- tiny precompute: vA,vB,c,s2 ----------------
__global__ void prep_kernel(const float* __restrict__ mlp_w1, const float* __restrict__ mlp_b1,
                            const float* __restrict__ mlp_w2, const float* __restrict__ mlp_b2,
                            const float* __restrict__ ust,
                            float* __restrict__ vB, float* __restrict__ s2)
{
    __shared__ float vA[64];
    __shared__ float csh;
    const int tid = threadIdx.x;   // 128
    if (tid < 64) {
        float a = 0.f;
        for (int f = 0; f < 64; ++f) a += mlp_w2[f] * mlp_w1[f * 128 + tid];
        vA[tid] = a;
    } else {
        const int g = tid - 64;
        float bsum = 0.f;
        for (int f = 0; f < 64; ++f) bsum += mlp_w2[f] * mlp_w1[f * 128 + 64 + g];
        vB[g] = bsum;
    }
    if (tid == 0) {
        float c = mlp_b2[0];
        for (int f = 0; f < 64; ++f) c += mlp_b1[f] * mlp_w2[f];
        csh = c;
    }
    __syncthreads();
    float s = csh;
    const float* ub = ust + (size_t)tid * F_;
    for (int g = 0; g < 64; ++g) s += ub[g] * vA[g];
    s2[tid] = s;
}

// um bf16: col a = ust[b]@emb[:,a]; col 5000+a = tanh(s2[b] + vB@emb[:,a]); pads 0
__global__ void um3_kernel(const float* __restrict__ ust, const float* __restrict__ emb,
                           const float* __restrict__ s2, const float* __restrict__ vB,
                           short* __restrict__ umb)
{
    const int b = blockIdx.y;
    __shared__ float us[64];
    __shared__ float vb[64];
    if (threadIdx.x < 64) {
        us[threadIdx.x] = ust[(size_t)b * F_ + threadIdx.x];
        vb[threadIdx.x] = vB[threadIdx.x];
    }
    __syncthreads();
    const int a = blockIdx.x * 256 + threadIdx.x;
    if (a < A_) {
        float accm = 0.f, acct = 0.f;
        #pragma unroll
        for (int g = 0; g < 64; ++g) {
            const float ev = emb[(size_t)g * A_ + a];
            accm += us[g] * ev;
            acct += vb[g] * ev;
        }
        umb[(size_t)b * KP2_ + a] = (short)f2bf(accm);
        umb[(size_t)b * KP2_ + A_ + a] = (short)f2bf(tanhf(s2[b] + acct));
    } else if (a < A_ + 48) {
        umb[(size_t)b * KP2_ + A_ + a] = 0;
    }
}

// ---------------- launch ----------------
extern "C" void kernel_launch(void* const* d_in, const int* in_sizes, int n_in,
                              void* d_out, int out_size, void* d_ws, size_t ws_size,
                              hipStream_t stream)
{
    const float* x       = (const float*)d_in[0];
    const float* conv_w2 = (const float*)d_in[1];
    const float* conv_b2 = (const float*)d_in[2];
    const float* conv_w3 = (const float*)d_in[3];
    const float* conv_b3 = (const float*)d_in[4];
    const float* conv_w4 = (const float*)d_in[5];
    const float* conv_b4 = (const float*)d_in[6];
    const float* conv_w5 = (const float*)d_in[7];
    const float* conv_b5 = (const float*)d_in[8];
    const float* sc_fcl_w = (const float*)d_in[9];
    const float* sc_fcl_b = (const float*)d_in[10];
    const float* fic_fc_w = (const float*)d_in[11];
    const float* fic_fc_b = (const float*)d_in[12];
    const float* emb      = (const float*)d_in[13];
    const float* mlp_w1   = (const float*)d_in[14];
    const float* mlp_b1   = (const float*)d_in[15];
    const float* mlp_w2   = (const float*)d_in[16];
    const float* mlp_b2   = (const float*)d_in[17];
    const float* fic_fcl_w = (const float*)d_in[18];
    const float* fic_fcl_b = (const float*)d_in[19];
    const float* fusion_w  = (const float*)d_in[20];
    const float* fusion_b  = (const float*)d_in[21];
    const float* task_w    = (const float*)d_in[22];
    const float* task_b    = (const float*)d_in[23];

    float* ws = (float*)d_ws;
    short* xp     = (short*)(ws + OFF_XP);
    short* wp     = (short*)(ws + OFF_WP);
    float* e      = ws + OFF_E;
    short* ebf    = (short*)(ws + OFF_EBF);
    float* ust    = ws + OFF_UST;
    float* vB     = ws + OFF_VB;
    float* s2     = ws + OFF_S2;
    short* umbf   = (short*)(ws + OFF_UMBF);
    short* ufbf   = (short*)(ws + OFF_UFBF);
    short* ummfbf = (short*)(ws + OFF_UMMFBF);
    float* part   = ws + OFF_PART;
    float* out    = (float*)d_out;

    // 1-2. preps
    prep_x_kernel<<<dim3(LP_, B_), CP_, 0, stream>>>(x, xp);
    prep_w_kernel<<<(128*14*CP_ + 255)/256, 256, 0, stream>>>(conv_w2, conv_w3, conv_w4, conv_w5, wp);

    // 3. conv v4 -> e + ebf (512 blocks, 2/CU, one round)
    conv_gemm4_kernel<<<dim3(B_, 4), 256, 0, stream>>>(xp, wp, conv_b2, conv_b3, conv_b4, conv_b5, e, ebf);

    // 4-5. u_sc -> ufbf cols [0,5000)
    gemm3_kernel<<<dim3(79, 4), 512, 0, stream>>>(ebf, D_, sc_fcl_w, D_, A_, 2, part);
    reduce2_kernel<<<(B_*A_ + 255)/256, 256, 0, stream>>>(part, sc_fcl_b, nullptr, ufbf, A_, KP2_, 0, 4, 0, 0);

    // 6. ust
    ust_kernel<<<B_, 256, 0, stream>>>(e, fic_fc_w, fic_fc_b, ust);

    // 7-8. mlp collapse + um
    prep_kernel<<<1, 128, 0, stream>>>(mlp_w1, mlp_b1, mlp_w2, mlp_b2, ust, vB, s2);
    um3_kernel<<<dim3(20, B_), 256, 0, stream>>>(ust, emb, s2, vB, umbf);

    // 9-10. u_fic -> ufbf cols [5000,10000) + pad
    gemm3_kernel<<<dim3(79, 12), 512, 0, stream>>>(umbf, KP2_, fic_fcl_w, 2*A_, A_, 14, part);
    reduce2_kernel<<<(B_*(A_+48) + 255)/256, 256, 0, stream>>>(part, fic_fcl_b, nullptr, ufbf, A_, KP2_, A_, 12, 1, 48);

    // 11-12. u_mmf -> ummfbf + pad
    gemm3_kernel<<<dim3(79, 12), 512, 0, stream>>>(ufbf, KP2_, fusion_w, 2*A_, A_, 14, part);
    reduce2_kernel<<<(B_*(A_+56) + 255)/256, 256, 0, stream>>>(part, fusion_b, nullptr, ummfbf, A_, KP1_, 0, 12, 0, 56);

    // 13-14. task -> out (fp32)
    gemm3_kernel<<<dim3(79, 12), 512, 0, stream>>>(ummfbf, KP1_, task_w, A_, A_, 7, part);
    reduce2_kernel<<<(B_*A_ + 255)/256, 256, 0, stream>>>(part, task_b, out, nullptr, A_, A_, 0, 12, 0, 0);
}